// Round 12
// baseline (680.603 us; speedup 1.0000x reference)
//
#include <hip/hip_runtime.h>

typedef __attribute__((ext_vector_type(4))) float f32x4;
typedef __attribute__((ext_vector_type(8))) short bf16x8;

constexpr int TOK = 8192;   // B*S
constexpr int DD  = 1024;   // D
constexpr int HH  = 2048;   // H
constexpr int NE  = 8;      // experts

// ---- workspace layout (bytes) ----
// 0      topk_idx   int[16384]        [0, 65536)
// 65536  topk_prob  f32[16384]        [65536, 131072)
// 131072 counts int[8]; 131104 cursor int[8]; 131136 offsets int[9]
// 131264 token_list int[16384]        [131264, 196800)
// 196800 prob_list  f32[16384]        [196800, 262336)
// 263552 dn_tab     int2[136]         [263552, 264640)
// 264640 dn_total   int
// 524288            x_bf   bf16[8192*1024]      (16.8 MB)
// 17301504          gw_bf  bf16[8*2048*1024]    (33.6 MB)
// 50855936          uw_bf  bf16[8*2048*1024]    (33.6 MB)
// 84410368          dw_bf  bf16[8*1024*2048]    (33.6 MB)
// 117964800         act    bf16[16384*2048]     (67.1 MB)
// total need: 185,073,664 B. Every buffer rewritten before read each call.

__device__ __forceinline__ unsigned short f2bf(float f) {
    union { float f; unsigned u; } v; v.f = f;
    unsigned r = v.u + 0x7fffu + ((v.u >> 16) & 1u);   // RNE
    return (unsigned short)(r >> 16);
}

__device__ __forceinline__ void gl2lds16(const void* g, void* l) {
    __builtin_amdgcn_global_load_lds(
        (const __attribute__((address_space(1))) unsigned int*)g,
        (__attribute__((address_space(3))) unsigned int*)l, 16, 0, 0);
}

// ------------- router: logits, top-2, probs; also emits x in bf16 -------------
__global__ __launch_bounds__(256) void k_router(
    const float* __restrict__ x, const float* __restrict__ rw,
    int* __restrict__ topk_idx, float* __restrict__ topk_prob,
    int* __restrict__ counts, unsigned short* __restrict__ x_bf)
{
    int wave = threadIdx.x >> 6;
    int lane = threadIdx.x & 63;
    int t = blockIdx.x * 4 + wave;

    const float4* xr = (const float4*)(x + (size_t)t * DD);
    float4 xv[4];
#pragma unroll
    for (int i = 0; i < 4; i++) xv[i] = xr[lane + 64 * i];

#pragma unroll
    for (int i = 0; i < 4; i++) {
        ushort4 u4 = make_ushort4(f2bf(xv[i].x), f2bf(xv[i].y),
                                  f2bf(xv[i].z), f2bf(xv[i].w));
        *(ushort4*)(x_bf + (size_t)t * DD + (lane + 64 * i) * 4) = u4;
    }

    float acc[NE];
#pragma unroll
    for (int e = 0; e < NE; e++) {
        const float4* wr = (const float4*)(rw + (size_t)e * DD);
        float s = 0.f;
#pragma unroll
        for (int i = 0; i < 4; i++) {
            float4 w = wr[lane + 64 * i];
            s += xv[i].x * w.x + xv[i].y * w.y + xv[i].z * w.z + xv[i].w * w.w;
        }
        acc[e] = s;
    }
#pragma unroll
    for (int e = 0; e < NE; e++) {
        float s = acc[e];
        for (int m = 32; m >= 1; m >>= 1) s += __shfl_xor(s, m);
        acc[e] = s;
    }
    if (lane == 0) {
        int b0 = 0; float l0 = acc[0];
#pragma unroll
        for (int e = 1; e < NE; e++) if (acc[e] > l0) { l0 = acc[e]; b0 = e; }
        int b1 = -1; float l1 = -3.0e38f;
#pragma unroll
        for (int e = 0; e < NE; e++) if (e != b0 && acc[e] > l1) { l1 = acc[e]; b1 = e; }
        float p0 = 1.f / (1.f + __expf(l1 - l0));
        float p1 = 1.f - p0;
        topk_idx[t * 2 + 0] = b0;  topk_idx[t * 2 + 1] = b1;
        topk_prob[t * 2 + 0] = p0; topk_prob[t * 2 + 1] = p1;
        atomicAdd(&counts[b0], 1);
        atomicAdd(&counts[b1], 1);
    }
}

// scan: offsets + flat 128-row tile table for down
__global__ void k_scan(const int* __restrict__ counts, int* __restrict__ offsets,
                       int2* __restrict__ dn_tab, int* __restrict__ dn_total)
{
    if (threadIdx.x == 0) {
        int s = 0;
        int cnt[NE];
        for (int e = 0; e < NE; e++) {
            cnt[e] = counts[e];
            offsets[e] = s; s += cnt[e];
        }
        offsets[NE] = s;
        int d = 0;
        for (int e = 0; e < NE; e++) {
            int mt = (cnt[e] + 127) >> 7;
            for (int m = 0; m < mt; m++) dn_tab[d++] = make_int2(e, m << 7);
        }
        *dn_total = d;
    }
}

__global__ __launch_bounds__(256) void k_scatter(
    const int* __restrict__ topk_idx, const float* __restrict__ topk_prob,
    const int* __restrict__ offsets, int* __restrict__ cursor,
    int* __restrict__ token_list, float* __restrict__ prob_list)
{
    int t = blockIdx.x * 256 + threadIdx.x;
#pragma unroll
    for (int k = 0; k < 2; k++) {
        int e = topk_idx[t * 2 + k];
        int pos = atomicAdd(&cursor[e], 1);
        token_list[offsets[e] + pos] = t;
        prob_list[offsets[e] + pos] = topk_prob[t * 2 + k];
    }
}

// ---------------- merged f32 -> bf16 weight convert ----------------
__global__ __launch_bounds__(256) void k_cvt_all(
    const float* __restrict__ gw, const float* __restrict__ uw,
    const float* __restrict__ dw,
    unsigned short* __restrict__ gwb, unsigned short* __restrict__ uwb,
    unsigned short* __restrict__ dwb)
{
    constexpr int SEG = NE * HH * DD / 8;
    int i = blockIdx.x * blockDim.x + threadIdx.x;
    int stride = gridDim.x * blockDim.x;
    for (; i < 3 * SEG; i += stride) {
        const float* in; unsigned short* out; int j = i;
        if (j < SEG)            { in = gw; out = gwb; }
        else if (j < 2 * SEG)   { in = uw; out = uwb; j -= SEG; }
        else                    { in = dw; out = dwb; j -= 2 * SEG; }
        const float4* p = (const float4*)(in + (size_t)j * 8);
        float4 a = p[0], b = p[1];
        uint4 v;
        v.x = (unsigned)f2bf(a.x) | ((unsigned)f2bf(a.y) << 16);
        v.y = (unsigned)f2bf(a.z) | ((unsigned)f2bf(a.w) << 16);
        v.z = (unsigned)f2bf(b.x) | ((unsigned)f2bf(b.y) << 16);
        v.w = (unsigned)f2bf(b.z) | ((unsigned)f2bf(b.w) << 16);
        *(uint4*)(out + (size_t)j * 8) = v;
    }
}

// ================ gateup (r6 exact, best measured): BM=128, B-rows=256, BK=64 ================
// Ring-3 LDS, depth-2 prefetch, counted vmcnt(6). Expert-pinned-to-XCD, n-inner.
__global__ __launch_bounds__(512) void k_gateup_v3(
    const unsigned short* __restrict__ xb,
    const unsigned short* __restrict__ gwb,
    const unsigned short* __restrict__ uwb,
    const int* __restrict__ offsets,
    const int* __restrict__ token_list,
    unsigned short* __restrict__ act)
{
    extern __shared__ char lds[];   // 3 * 49152: per buf A 16K | B(G+U) 32K

    const int bid = blockIdx.x;
    const int e   = bid & 7;            // expert == XCD
    const int r   = bid >> 3;
    const int m   = r >> 4;
    const int n   = r & 15;
    const int off = offsets[e];
    const int n_e = offsets[e + 1] - off;
    const int m0  = m * 128;
    if (m0 >= n_e) return;
    const int n0g = n * 128;

    const int tid = threadIdx.x, lane = tid & 63, wid = tid >> 6;
    const int wm = wid >> 2, wn = wid & 3;          // 2m x 4n
    const int l8 = lane >> 3;
    const int colb = ((lane & 7) * 16) ^ (l8 << 4);

    const char* src[6];
    unsigned ldsoff[6];
#pragma unroll
    for (int i = 0; i < 6; i++) {
        int c = wid * 6 + i;
        if (c < 16) {
            int tr = c * 8 + l8;
            int rg = m0 + tr; if (rg > n_e - 1) rg = n_e - 1;
            int tok = token_list[off + rg];
            src[i] = (const char*)xb + (size_t)tok * (DD * 2) + colb;
            ldsoff[i] = c * 1024u;
        } else {
            int cb = c - 16;
            int tr = cb * 8 + l8;
            int wr = tr >> 6, w = tr & 63;
            const unsigned short* W = (w < 32) ? gwb : uwb;
            int wcol = n0g + wr * 32 + (w & 31);
            src[i] = (const char*)W + ((size_t)e * HH + wcol) * (DD * 2) + colb;
            ldsoff[i] = 16384u + cb * 1024u;
        }
    }

    f32x4 acc[4][4] = {};   // nj 0,1 = gate; 2,3 = up

#define GU_STAGE(T) do { char* b_ = lds + ((T) % 3) * 49152u; \
    _Pragma("unroll") for (int i_ = 0; i_ < 6; i_++) \
        gl2lds16(src[i_] + (T) * 128, b_ + ldsoff[i_]); } while (0)

    GU_STAGE(0);
    GU_STAGE(1);
    asm volatile("s_waitcnt vmcnt(6)" ::: "memory");
    __builtin_amdgcn_s_barrier();
    asm volatile("" ::: "memory");

    constexpr int NT = (DD * 2) / 128;   // 16 K-tiles
    for (int t = 0; t < NT; ++t) {
        if (t + 2 < NT) GU_STAGE(t + 2);
        const char* La = lds + (t % 3) * 49152u;
        const char* Lb = La + 16384;
        __builtin_amdgcn_s_setprio(1);
#pragma unroll
        for (int kk = 0; kk < 2; kk++) {
            const int kb = kk * 64 + (lane >> 4) * 16;
            bf16x8 af[4], bfr[4];
#pragma unroll
            for (int mi = 0; mi < 4; mi++) {
                int row = wm * 64 + mi * 16 + (lane & 15);
                af[mi] = *(const bf16x8*)(La + row * 128 + (kb ^ ((row & 7) << 4)));
            }
#pragma unroll
            for (int nj = 0; nj < 4; nj++) {
                int br = wn * 64 + nj * 16 + (lane & 15);
                bfr[nj] = *(const bf16x8*)(Lb + br * 128 + (kb ^ ((br & 7) << 4)));
            }
#pragma unroll
            for (int mi = 0; mi < 4; mi++)
#pragma unroll
                for (int nj = 0; nj < 4; nj++)
                    acc[mi][nj] = __builtin_amdgcn_mfma_f32_16x16x32_bf16(af[mi], bfr[nj], acc[mi][nj], 0, 0, 0);
        }
        __builtin_amdgcn_s_setprio(0);
        if (t + 2 < NT)      asm volatile("s_waitcnt vmcnt(6)" ::: "memory");
        else if (t + 1 < NT) asm volatile("s_waitcnt vmcnt(0)" ::: "memory");
        __builtin_amdgcn_s_barrier();
        asm volatile("" ::: "memory");
    }
#undef GU_STAGE

    // epilogue: silu(g)*u -> act bf16
#pragma unroll
    for (int mi = 0; mi < 4; mi++) {
#pragma unroll
        for (int r2 = 0; r2 < 4; r2++) {
            int row = wm * 64 + mi * 16 + (lane >> 4) * 4 + r2;
            int rg = m0 + row;
            if (rg >= n_e) continue;
            size_t rowbase = (size_t)(off + rg) * HH + n0g + wn * 32;
#pragma unroll
            for (int nj = 0; nj < 2; nj++) {
                float gg = acc[mi][nj][r2];
                float uu = acc[mi][nj + 2][r2];
                float sv = gg / (1.f + __expf(-gg)) * uu;
                act[rowbase + nj * 16 + (lane & 15)] = f2bf(sv);
            }
        }
    }
}

// ================ down (r10 v6 body): BM=128 x BN=256, flat tile table ================
// Epilogue: weighted f32 atomicAdd directly into out (no y, no combine).
__global__ __launch_bounds__(512) void k_down_v6(
    const unsigned short* __restrict__ act,
    const unsigned short* __restrict__ dwb,
    const int* __restrict__ offsets,
    const int* __restrict__ token_list,
    const float* __restrict__ prob_list,
    const int2* __restrict__ dn_tab,
    const int* __restrict__ dn_total,
    float* __restrict__ out)
{
    extern __shared__ char lds[];   // 3 * 49152: per buf A 16K | B 32K

    const int bid = blockIdx.x;
    const int wg  = (bid & 7) * 68 + (bid >> 3);
    const int n   = wg / 136;
    const int mt  = wg % 136;
    if (mt >= *dn_total) return;
    const int2 em = dn_tab[mt];
    const int e   = em.x;
    const int m0  = em.y;
    const int off = offsets[e];
    const int n_e = offsets[e + 1] - off;
    const int n0  = n * 256;            // D col base

    const int tid = threadIdx.x, lane = tid & 63, wid = tid >> 6;
    const int wm = wid >> 2, wn = wid & 3;
    const int l8 = lane >> 3;
    const int colb = ((lane & 7) * 16) ^ (l8 << 4);

    const char* src[6];
    unsigned ldsoff[6];
#pragma unroll
    for (int i = 0; i < 6; i++) {
        int c = wid * 6 + i;
        if (c < 16) {
            int tr = c * 8 + l8;
            int rg = m0 + tr; if (rg > n_e - 1) rg = n_e - 1;
            src[i] = (const char*)act + (size_t)(off + rg) * (HH * 2) + colb;
            ldsoff[i] = c * 1024u;
        } else {
            int cb = c - 16;
            int tr = cb * 8 + l8;
            src[i] = (const char*)dwb + ((size_t)e * DD + n0 + tr) * (HH * 2) + colb;
            ldsoff[i] = 16384u + cb * 1024u;
        }
    }

    f32x4 acc[4][4] = {};

#define DN_STAGE(T) do { char* b_ = lds + ((T) % 3) * 49152u; \
    _Pragma("unroll") for (int i_ = 0; i_ < 6; i_++) \
        gl2lds16(src[i_] + (T) * 128, b_ + ldsoff[i_]); } while (0)

    DN_STAGE(0);
    DN_STAGE(1);
    asm volatile("s_waitcnt vmcnt(6)" ::: "memory");
    __builtin_amdgcn_s_barrier();
    asm volatile("" ::: "memory");

    constexpr int NT = (HH * 2) / 128;   // 32 K-tiles
    for (int t = 0; t < NT; ++t) {
        if (t + 2 < NT) DN_STAGE(t + 2);
        const char* La = lds + (t % 3) * 49152u;
        const char* Lb = La + 16384;
        __builtin_amdgcn_s_setprio(1);
#pragma unroll
        for (int kk = 0; kk < 2; kk++) {
            const int kb = kk * 64 + (lane >> 4) * 16;
            bf16x8 af[4], bfr[4];
#pragma unroll
            for (int mi = 0; mi < 4; mi++) {
                int row = wm * 64 + mi * 16 + (lane & 15);
                af[mi] = *(const bf16x8*)(La + row * 128 + (kb ^ ((row & 7) << 4)));
            }
#pragma unroll
            for (int nj = 0; nj < 4; nj++) {
                int br = wn * 64 + nj * 16 + (lane & 15);
                bfr[nj] = *(const bf16x8*)(Lb + br * 128 + (kb ^ ((br & 7) << 4)));
            }
#pragma unroll
            for (int mi = 0; mi < 4; mi++)
#pragma unroll
                for (int nj = 0; nj < 4; nj++)
                    acc[mi][nj] = __builtin_amdgcn_mfma_f32_16x16x32_bf16(af[mi], bfr[nj], acc[mi][nj], 0, 0, 0);
        }
        __builtin_amdgcn_s_setprio(0);
        if (t + 2 < NT)      asm volatile("s_waitcnt vmcnt(6)" ::: "memory");
        else if (t + 1 < NT) asm volatile("s_waitcnt vmcnt(0)" ::: "memory");
        __builtin_amdgcn_s_barrier();
        asm volatile("" ::: "memory");
    }
#undef DN_STAGE

    // epilogue: out[token] += prob * result (f32 atomics; 2 contributors/token)
#pragma unroll
    for (int mi = 0; mi < 4; mi++) {
#pragma unroll
        for (int r2 = 0; r2 < 4; r2++) {
            int row = wm * 64 + mi * 16 + (lane >> 4) * 4 + r2;
            int rg = m0 + row;
            if (rg >= n_e) continue;
            int tok = token_list[off + rg];
            float p = prob_list[off + rg];
            size_t obase = (size_t)tok * DD + n0 + wn * 64;
#pragma unroll
            for (int nj = 0; nj < 4; nj++)
                atomicAdd(&out[obase + nj * 16 + (lane & 15)], acc[mi][nj][r2] * p);
        }
    }
}

extern "C" void kernel_launch(void* const* d_in, const int* in_sizes, int n_in,
                              void* d_out, int out_size, void* d_ws, size_t ws_size,
                              hipStream_t stream) {
    const float* x  = (const float*)d_in[0];
    const float* rw = (const float*)d_in[1];
    const float* gw = (const float*)d_in[2];
    const float* uw = (const float*)d_in[3];
    const float* dw = (const float*)d_in[4];
    float* out = (float*)d_out;

    char* ws = (char*)d_ws;
    int*   topk_idx   = (int*)(ws + 0);
    float* topk_prob  = (float*)(ws + 65536);
    int*   counts     = (int*)(ws + 131072);
    int*   cursor     = (int*)(ws + 131104);
    int*   offsets    = (int*)(ws + 131136);
    int*   token_list = (int*)(ws + 131264);
    float* prob_list  = (float*)(ws + 196800);
    int2*  dn_tab     = (int2*)(ws + 263552);
    int*   dn_total   = (int*)(ws + 264640);

    unsigned short* x_bf  = (unsigned short*)(ws + 524288);
    unsigned short* gw_bf = (unsigned short*)(ws + 17301504);
    unsigned short* uw_bf = (unsigned short*)(ws + 50855936);
    unsigned short* dw_bf = (unsigned short*)(ws + 84410368);
    unsigned short* act   = (unsigned short*)(ws + 117964800);

    hipMemsetAsync(ws + 131072, 0, 64, stream);   // counts + cursor
    hipMemsetAsync(d_out, 0, (size_t)out_size * sizeof(float), stream);

    k_router<<<TOK / 4, 256, 0, stream>>>(x, rw, topk_idx, topk_prob, counts, x_bf);
    k_scan<<<1, 64, 0, stream>>>(counts, offsets, dn_tab, dn_total);
    k_scatter<<<TOK / 256, 256, 0, stream>>>(topk_idx, topk_prob, offsets, cursor,
                                             token_list, prob_list);

    k_cvt_all<<<4096, 256, 0, stream>>>(gw, uw, dw, gw_bf, uw_bf, dw_bf);

    // gateup: r6 exact mapping (fastest measured: 210 us)
    k_gateup_v3<<<16384, 512, 147456, stream>>>(x_bf, gw_bf, uw_bf, offsets,
                                                token_list, act);
    // down: 544 blocks = 4 n x 136 (128-row) tile slots, XCD-chunked; atomic out
    k_down_v6<<<544, 512, 147456, stream>>>(act, dw_bf, offsets, token_list,
                                            prob_list, dn_tab, dn_total, out);
}

// Round 14
// 382.184 us; speedup vs baseline: 1.7808x; 1.7808x over previous
//
#include <hip/hip_runtime.h>

typedef __attribute__((ext_vector_type(4))) float f32x4;
typedef __attribute__((ext_vector_type(8))) short bf16x8;

constexpr int TOK = 8192;   // B*S
constexpr int DD  = 1024;   // D
constexpr int HH  = 2048;   // H
constexpr int NE  = 8;      // experts
constexpr int SB  = TOK / 256;   // 32 scatter/hist blocks — MUST match k_scan2 loop

// ---- workspace layout (bytes) ----
// 0      topk_idx   int[16384]        [0, 65536)
// 65536  topk_prob  f32[16384]        [65536, 131072)
// 131072 offsets    int[9]            [131072, 131108)
// 131136 blk_hist   int[SB=32][8]     [131136, 132160)
// 133184 base       int[32][8]        [133184, 134208)
// 135232 dn_tab     int2[136]         [135232, 136320)
// 136320 dn_total   int
// 137216 token_list int[16384]        [137216, 202752)
// 202752 prob_list  f32[16384]        [202752, 268288)
// 268288 slot       int[16384]        [268288, 333824)
// 524288            x_bf   bf16[8192*1024]      (16.8 MB)  [dead after gateup]
// 524288            y      bf16[16384*1024]     (33.5 MB)  [overlays x_bf/gw_bf]
// 17301504          gw_bf  bf16[8*2048*1024]    (33.6 MB)  [dead after gateup]
// 50855936          uw_bf  bf16[8*2048*1024]    (33.6 MB)  [dead after gateup]
// 84410368          dw_bf  bf16[8*1024*2048]    (33.6 MB)
// 117964800         act    bf16[16384*2048]     (67.1 MB)
// total need: 185,073,664 B. Every buffer rewritten before read each call.

__device__ __forceinline__ unsigned short f2bf(float f) {
    union { float f; unsigned u; } v; v.f = f;
    unsigned r = v.u + 0x7fffu + ((v.u >> 16) & 1u);   // RNE
    return (unsigned short)(r >> 16);
}

__device__ __forceinline__ void gl2lds16(const void* g, void* l) {
    __builtin_amdgcn_global_load_lds(
        (const __attribute__((address_space(1))) unsigned int*)g,
        (__attribute__((address_space(3))) unsigned int*)l, 16, 0, 0);
}

// ------------- router: logits, top-2, probs; emits x bf16. NO global atomics -------------
__global__ __launch_bounds__(256) void k_router(
    const float* __restrict__ x, const float* __restrict__ rw,
    int* __restrict__ topk_idx, float* __restrict__ topk_prob,
    unsigned short* __restrict__ x_bf)
{
    int wave = threadIdx.x >> 6;
    int lane = threadIdx.x & 63;
    int t = blockIdx.x * 4 + wave;

    const float4* xr = (const float4*)(x + (size_t)t * DD);
    float4 xv[4];
#pragma unroll
    for (int i = 0; i < 4; i++) xv[i] = xr[lane + 64 * i];

#pragma unroll
    for (int i = 0; i < 4; i++) {
        ushort4 u4 = make_ushort4(f2bf(xv[i].x), f2bf(xv[i].y),
                                  f2bf(xv[i].z), f2bf(xv[i].w));
        *(ushort4*)(x_bf + (size_t)t * DD + (lane + 64 * i) * 4) = u4;
    }

    float acc[NE];
#pragma unroll
    for (int e = 0; e < NE; e++) {
        const float4* wr = (const float4*)(rw + (size_t)e * DD);
        float s = 0.f;
#pragma unroll
        for (int i = 0; i < 4; i++) {
            float4 w = wr[lane + 64 * i];
            s += xv[i].x * w.x + xv[i].y * w.y + xv[i].z * w.z + xv[i].w * w.w;
        }
        acc[e] = s;
    }
#pragma unroll
    for (int e = 0; e < NE; e++) {
        float s = acc[e];
        for (int m = 32; m >= 1; m >>= 1) s += __shfl_xor(s, m);
        acc[e] = s;
    }
    if (lane == 0) {
        int b0 = 0; float l0 = acc[0];
#pragma unroll
        for (int e = 1; e < NE; e++) if (acc[e] > l0) { l0 = acc[e]; b0 = e; }
        int b1 = -1; float l1 = -3.0e38f;
#pragma unroll
        for (int e = 0; e < NE; e++) if (e != b0 && acc[e] > l1) { l1 = acc[e]; b1 = e; }
        float p0 = 1.f / (1.f + __expf(l1 - l0));
        float p1 = 1.f - p0;
        topk_idx[t * 2 + 0] = b0;  topk_idx[t * 2 + 1] = b1;
        topk_prob[t * 2 + 0] = p0; topk_prob[t * 2 + 1] = p1;
    }
}

// ------------- per-block histogram (LDS atomics only); SB blocks -------------
__global__ __launch_bounds__(256) void k_hist(
    const int* __restrict__ topk_idx, int* __restrict__ blk_hist)
{
    __shared__ int h[NE];
    if (threadIdx.x < NE) h[threadIdx.x] = 0;
    __syncthreads();
    int t = blockIdx.x * 256 + threadIdx.x;
    atomicAdd(&h[topk_idx[t * 2 + 0]], 1);
    atomicAdd(&h[topk_idx[t * 2 + 1]], 1);
    __syncthreads();
    if (threadIdx.x < NE)
        blk_hist[blockIdx.x * NE + threadIdx.x] = h[threadIdx.x];
}

// ------------- cross-block prefix + offsets + down tile table (SB blocks) -------------
__global__ void k_scan2(const int* __restrict__ blk_hist, int* __restrict__ offsets,
                        int* __restrict__ base, int2* __restrict__ dn_tab,
                        int* __restrict__ dn_total)
{
    __shared__ int totals[NE];
    int e = threadIdx.x;
    if (e < NE) {
        int run = 0;
        for (int b = 0; b < SB; b++) {
            base[b * NE + e] = run;
            run += blk_hist[b * NE + e];
        }
        totals[e] = run;
    }
    __syncthreads();
    if (threadIdx.x == 0) {
        int s = 0;
        for (int ee = 0; ee < NE; ee++) { offsets[ee] = s; s += totals[ee]; }
        offsets[NE] = s;
        int d = 0;
        for (int ee = 0; ee < NE; ee++) {
            int mt = (totals[ee] + 127) >> 7;
            for (int m = 0; m < mt; m++) dn_tab[d++] = make_int2(ee, m << 7);
        }
        *dn_total = d;
    }
    __syncthreads();
    if (e < NE) {
        int o = offsets[e];
        for (int b = 0; b < SB; b++) base[b * NE + e] += o;
    }
}

// ------------- scatter via LDS cursors (no contended global atomics); SB blocks -------------
__global__ __launch_bounds__(256) void k_scatter2(
    const int* __restrict__ topk_idx, const float* __restrict__ topk_prob,
    const int* __restrict__ base,
    int* __restrict__ token_list, float* __restrict__ prob_list,
    int* __restrict__ slot)
{
    __shared__ int cur[NE];
    if (threadIdx.x < NE) cur[threadIdx.x] = base[blockIdx.x * NE + threadIdx.x];
    __syncthreads();
    int t = blockIdx.x * 256 + threadIdx.x;
#pragma unroll
    for (int k = 0; k < 2; k++) {
        int e = topk_idx[t * 2 + k];
        int pos = atomicAdd(&cur[e], 1);   // LDS atomic
        token_list[pos] = t;
        prob_list[pos] = topk_prob[t * 2 + k];
        slot[t * 2 + k] = pos;
    }
}

// ---------------- merged f32 -> bf16 weight convert ----------------
__global__ __launch_bounds__(256) void k_cvt_all(
    const float* __restrict__ gw, const float* __restrict__ uw,
    const float* __restrict__ dw,
    unsigned short* __restrict__ gwb, unsigned short* __restrict__ uwb,
    unsigned short* __restrict__ dwb)
{
    constexpr int SEG = NE * HH * DD / 8;
    int i = blockIdx.x * blockDim.x + threadIdx.x;
    int stride = gridDim.x * blockDim.x;
    for (; i < 3 * SEG; i += stride) {
        const float* in; unsigned short* out; int j = i;
        if (j < SEG)            { in = gw; out = gwb; }
        else if (j < 2 * SEG)   { in = uw; out = uwb; j -= SEG; }
        else                    { in = dw; out = dwb; j -= 2 * SEG; }
        const float4* p = (const float4*)(in + (size_t)j * 8);
        float4 a = p[0], b = p[1];
        uint4 v;
        v.x = (unsigned)f2bf(a.x) | ((unsigned)f2bf(a.y) << 16);
        v.y = (unsigned)f2bf(a.z) | ((unsigned)f2bf(a.w) << 16);
        v.z = (unsigned)f2bf(b.x) | ((unsigned)f2bf(b.y) << 16);
        v.w = (unsigned)f2bf(b.z) | ((unsigned)f2bf(b.w) << 16);
        *(uint4*)(out + (size_t)j * 8) = v;
    }
}

// ================ gateup (r6 exact, best measured): BM=128, B-rows=256, BK=64 ================
__global__ __launch_bounds__(512) void k_gateup_v3(
    const unsigned short* __restrict__ xb,
    const unsigned short* __restrict__ gwb,
    const unsigned short* __restrict__ uwb,
    const int* __restrict__ offsets,
    const int* __restrict__ token_list,
    unsigned short* __restrict__ act)
{
    extern __shared__ char lds[];   // 3 * 49152: per buf A 16K | B(G+U) 32K

    const int bid = blockIdx.x;
    const int e   = bid & 7;            // expert == XCD
    const int r   = bid >> 3;
    const int m   = r >> 4;
    const int n   = r & 15;
    const int off = offsets[e];
    const int n_e = offsets[e + 1] - off;
    const int m0  = m * 128;
    if (m0 >= n_e) return;
    const int n0g = n * 128;

    const int tid = threadIdx.x, lane = tid & 63, wid = tid >> 6;
    const int wm = wid >> 2, wn = wid & 3;          // 2m x 4n
    const int l8 = lane >> 3;
    const int colb = ((lane & 7) * 16) ^ (l8 << 4);

    const char* src[6];
    unsigned ldsoff[6];
#pragma unroll
    for (int i = 0; i < 6; i++) {
        int c = wid * 6 + i;
        if (c < 16) {
            int tr = c * 8 + l8;
            int rg = m0 + tr; if (rg > n_e - 1) rg = n_e - 1;
            int tok = token_list[off + rg];
            src[i] = (const char*)xb + (size_t)tok * (DD * 2) + colb;
            ldsoff[i] = c * 1024u;
        } else {
            int cb = c - 16;
            int tr = cb * 8 + l8;
            int wr = tr >> 6, w = tr & 63;
            const unsigned short* W = (w < 32) ? gwb : uwb;
            int wcol = n0g + wr * 32 + (w & 31);
            src[i] = (const char*)W + ((size_t)e * HH + wcol) * (DD * 2) + colb;
            ldsoff[i] = 16384u + cb * 1024u;
        }
    }

    f32x4 acc[4][4] = {};   // nj 0,1 = gate; 2,3 = up

#define GU_STAGE(T) do { char* b_ = lds + ((T) % 3) * 49152u; \
    _Pragma("unroll") for (int i_ = 0; i_ < 6; i_++) \
        gl2lds16(src[i_] + (T) * 128, b_ + ldsoff[i_]); } while (0)

    GU_STAGE(0);
    GU_STAGE(1);
    asm volatile("s_waitcnt vmcnt(6)" ::: "memory");
    __builtin_amdgcn_s_barrier();
    asm volatile("" ::: "memory");

    constexpr int NT = (DD * 2) / 128;   // 16 K-tiles
    for (int t = 0; t < NT; ++t) {
        if (t + 2 < NT) GU_STAGE(t + 2);
        const char* La = lds + (t % 3) * 49152u;
        const char* Lb = La + 16384;
        __builtin_amdgcn_s_setprio(1);
#pragma unroll
        for (int kk = 0; kk < 2; kk++) {
            const int kb = kk * 64 + (lane >> 4) * 16;
            bf16x8 af[4], bfr[4];
#pragma unroll
            for (int mi = 0; mi < 4; mi++) {
                int row = wm * 64 + mi * 16 + (lane & 15);
                af[mi] = *(const bf16x8*)(La + row * 128 + (kb ^ ((row & 7) << 4)));
            }
#pragma unroll
            for (int nj = 0; nj < 4; nj++) {
                int br = wn * 64 + nj * 16 + (lane & 15);
                bfr[nj] = *(const bf16x8*)(Lb + br * 128 + (kb ^ ((br & 7) << 4)));
            }
#pragma unroll
            for (int mi = 0; mi < 4; mi++)
#pragma unroll
                for (int nj = 0; nj < 4; nj++)
                    acc[mi][nj] = __builtin_amdgcn_mfma_f32_16x16x32_bf16(af[mi], bfr[nj], acc[mi][nj], 0, 0, 0);
        }
        __builtin_amdgcn_s_setprio(0);
        if (t + 2 < NT)      asm volatile("s_waitcnt vmcnt(6)" ::: "memory");
        else if (t + 1 < NT) asm volatile("s_waitcnt vmcnt(0)" ::: "memory");
        __builtin_amdgcn_s_barrier();
        asm volatile("" ::: "memory");
    }
#undef GU_STAGE

    // epilogue: silu(g)*u -> act bf16
#pragma unroll
    for (int mi = 0; mi < 4; mi++) {
#pragma unroll
        for (int r2 = 0; r2 < 4; r2++) {
            int row = wm * 64 + mi * 16 + (lane >> 4) * 4 + r2;
            int rg = m0 + row;
            if (rg >= n_e) continue;
            size_t rowbase = (size_t)(off + rg) * HH + n0g + wn * 32;
#pragma unroll
            for (int nj = 0; nj < 2; nj++) {
                float gg = acc[mi][nj][r2];
                float uu = acc[mi][nj + 2][r2];
                float sv = gg / (1.f + __expf(-gg)) * uu;
                act[rowbase + nj * 16 + (lane & 15)] = f2bf(sv);
            }
        }
    }
}

// ================ down (r10 exact): BM=128 x BN=256, flat tile table -> y bf16 ================
__global__ __launch_bounds__(512) void k_down_v6(
    const unsigned short* __restrict__ act,
    const unsigned short* __restrict__ dwb,
    const int* __restrict__ offsets,
    const int2* __restrict__ dn_tab,
    const int* __restrict__ dn_total,
    unsigned short* __restrict__ y)
{
    extern __shared__ char lds[];   // 3 * 49152: per buf A 16K | B 32K

    const int bid = blockIdx.x;
    const int wg  = (bid & 7) * 68 + (bid >> 3);
    const int n   = wg / 136;
    const int mt  = wg % 136;
    if (mt >= *dn_total) return;
    const int2 em = dn_tab[mt];
    const int e   = em.x;
    const int m0  = em.y;
    const int off = offsets[e];
    const int n_e = offsets[e + 1] - off;
    const int n0  = n * 256;            // D col base

    const int tid = threadIdx.x, lane = tid & 63, wid = tid >> 6;
    const int wm = wid >> 2, wn = wid & 3;
    const int l8 = lane >> 3;
    const int colb = ((lane & 7) * 16) ^ (l8 << 4);

    const char* src[6];
    unsigned ldsoff[6];
#pragma unroll
    for (int i = 0; i < 6; i++) {
        int c = wid * 6 + i;
        if (c < 16) {
            int tr = c * 8 + l8;
            int rg = m0 + tr; if (rg > n_e - 1) rg = n_e - 1;
            src[i] = (const char*)act + (size_t)(off + rg) * (HH * 2) + colb;
            ldsoff[i] = c * 1024u;
        } else {
            int cb = c - 16;
            int tr = cb * 8 + l8;
            src[i] = (const char*)dwb + ((size_t)e * DD + n0 + tr) * (HH * 2) + colb;
            ldsoff[i] = 16384u + cb * 1024u;
        }
    }

    f32x4 acc[4][4] = {};

#define DN_STAGE(T) do { char* b_ = lds + ((T) % 3) * 49152u; \
    _Pragma("unroll") for (int i_ = 0; i_ < 6; i_++) \
        gl2lds16(src[i_] + (T) * 128, b_ + ldsoff[i_]); } while (0)

    DN_STAGE(0);
    DN_STAGE(1);
    asm volatile("s_waitcnt vmcnt(6)" ::: "memory");
    __builtin_amdgcn_s_barrier();
    asm volatile("" ::: "memory");

    constexpr int NT = (HH * 2) / 128;   // 32 K-tiles
    for (int t = 0; t < NT; ++t) {
        if (t + 2 < NT) DN_STAGE(t + 2);
        const char* La = lds + (t % 3) * 49152u;
        const char* Lb = La + 16384;
        __builtin_amdgcn_s_setprio(1);
#pragma unroll
        for (int kk = 0; kk < 2; kk++) {
            const int kb = kk * 64 + (lane >> 4) * 16;
            bf16x8 af[4], bfr[4];
#pragma unroll
            for (int mi = 0; mi < 4; mi++) {
                int row = wm * 64 + mi * 16 + (lane & 15);
                af[mi] = *(const bf16x8*)(La + row * 128 + (kb ^ ((row & 7) << 4)));
            }
#pragma unroll
            for (int nj = 0; nj < 4; nj++) {
                int br = wn * 64 + nj * 16 + (lane & 15);
                bfr[nj] = *(const bf16x8*)(Lb + br * 128 + (kb ^ ((br & 7) << 4)));
            }
#pragma unroll
            for (int mi = 0; mi < 4; mi++)
#pragma unroll
                for (int nj = 0; nj < 4; nj++)
                    acc[mi][nj] = __builtin_amdgcn_mfma_f32_16x16x32_bf16(af[mi], bfr[nj], acc[mi][nj], 0, 0, 0);
        }
        __builtin_amdgcn_s_setprio(0);
        if (t + 2 < NT)      asm volatile("s_waitcnt vmcnt(6)" ::: "memory");
        else if (t + 1 < NT) asm volatile("s_waitcnt vmcnt(0)" ::: "memory");
        __builtin_amdgcn_s_barrier();
        asm volatile("" ::: "memory");
    }
#undef DN_STAGE

    // epilogue: y[grouped row] = result (bf16; combine applies probs)
#pragma unroll
    for (int mi = 0; mi < 4; mi++) {
#pragma unroll
        for (int r2 = 0; r2 < 4; r2++) {
            int row = wm * 64 + mi * 16 + (lane >> 4) * 4 + r2;
            int rg = m0 + row;
            if (rg >= n_e) continue;
            size_t ybase = (size_t)(off + rg) * DD + n0 + wn * 64;
#pragma unroll
            for (int nj = 0; nj < 4; nj++)
                y[ybase + nj * 16 + (lane & 15)] = f2bf(acc[mi][nj][r2]);
        }
    }
}

// ---------------- combine: out[t] = p0*y[slot0] + p1*y[slot1] ----------------
__global__ __launch_bounds__(256) void k_combine(
    const unsigned short* __restrict__ y,
    const int* __restrict__ slot,
    const float* __restrict__ topk_prob,
    float* __restrict__ out)
{
    int t = blockIdx.x * 2 + (threadIdx.x >> 7);
    int i = threadIdx.x & 127;
    int s0 = slot[t * 2 + 0], s1 = slot[t * 2 + 1];
    float p0 = topk_prob[t * 2 + 0], p1 = topk_prob[t * 2 + 1];
    bf16x8 a = *(const bf16x8*)(y + (size_t)s0 * DD + i * 8);
    bf16x8 b = *(const bf16x8*)(y + (size_t)s1 * DD + i * 8);
    float o[8];
#pragma unroll
    for (int j = 0; j < 8; j++) {
        union { unsigned u; float f; } va, vb;
        va.u = ((unsigned)(unsigned short)a[j]) << 16;
        vb.u = ((unsigned)(unsigned short)b[j]) << 16;
        o[j] = p0 * va.f + p1 * vb.f;
    }
    float4* op = (float4*)(out + (size_t)t * DD + i * 8);
    op[0] = make_float4(o[0], o[1], o[2], o[3]);
    op[1] = make_float4(o[4], o[5], o[6], o[7]);
}

extern "C" void kernel_launch(void* const* d_in, const int* in_sizes, int n_in,
                              void* d_out, int out_size, void* d_ws, size_t ws_size,
                              hipStream_t stream) {
    const float* x  = (const float*)d_in[0];
    const float* rw = (const float*)d_in[1];
    const float* gw = (const float*)d_in[2];
    const float* uw = (const float*)d_in[3];
    const float* dw = (const float*)d_in[4];
    float* out = (float*)d_out;

    char* ws = (char*)d_ws;
    int*   topk_idx   = (int*)(ws + 0);
    float* topk_prob  = (float*)(ws + 65536);
    int*   offsets    = (int*)(ws + 131072);
    int*   blk_hist   = (int*)(ws + 131136);
    int*   base       = (int*)(ws + 133184);
    int2*  dn_tab     = (int2*)(ws + 135232);
    int*   dn_total   = (int*)(ws + 136320);
    int*   token_list = (int*)(ws + 137216);
    float* prob_list  = (float*)(ws + 202752);
    int*   slot       = (int*)(ws + 268288);

    unsigned short* x_bf  = (unsigned short*)(ws + 524288);
    unsigned short* y     = (unsigned short*)(ws + 524288);  // overlays x_bf/gw_bf (dead)
    unsigned short* gw_bf = (unsigned short*)(ws + 17301504);
    unsigned short* uw_bf = (unsigned short*)(ws + 50855936);
    unsigned short* dw_bf = (unsigned short*)(ws + 84410368);
    unsigned short* act   = (unsigned short*)(ws + 117964800);

    k_router<<<TOK / 4, 256, 0, stream>>>(x, rw, topk_idx, topk_prob, x_bf);
    k_hist<<<SB, 256, 0, stream>>>(topk_idx, blk_hist);
    k_scan2<<<1, 64, 0, stream>>>(blk_hist, offsets, base, dn_tab, dn_total);
    k_scatter2<<<SB, 256, 0, stream>>>(topk_idx, topk_prob, base,
                                       token_list, prob_list, slot);

    k_cvt_all<<<2048, 256, 0, stream>>>(gw, uw, dw, gw_bf, uw_bf, dw_bf);

    // gateup: r6 exact mapping (fastest measured: 210 us)
    k_gateup_v3<<<16384, 512, 147456, stream>>>(x_bf, gw_bf, uw_bf, offsets,
                                                token_list, act);
    // down: 544 blocks = 4 n x 136 (128-row) tile slots, XCD-chunked
    k_down_v6<<<544, 512, 147456, stream>>>(act, dw_bf, offsets, dn_tab,
                                            dn_total, y);

    k_combine<<<TOK / 2, 256, 0, stream>>>(y, slot, topk_prob, out);
}

// Round 15
// 368.122 us; speedup vs baseline: 1.8488x; 1.0382x over previous
//
#include <hip/hip_runtime.h>

typedef __attribute__((ext_vector_type(4))) float f32x4;
typedef __attribute__((ext_vector_type(8))) short bf16x8;

constexpr int TOK = 8192;   // B*S
constexpr int DD  = 1024;   // D
constexpr int HH  = 2048;   // H
constexpr int NE  = 8;      // experts
constexpr int SB  = TOK / 256;   // 32 scatter/hist blocks — MUST match k_scan2 loop

// ---- workspace layout (bytes) ----
// 0      topk_idx   int[16384]        [0, 65536)
// 65536  topk_prob  f32[16384]        [65536, 131072)
// 131072 offsets    int[9]            [131072, 131108)
// 131136 blk_hist   int[SB=32][8]     [131136, 132160)
// 133184 base       int[32][8]        [133184, 134208)
// 137216 token_list int[16384]        [137216, 202752)
// 202752 prob_list  f32[16384]        [202752, 268288)
// 268288 slot       int[16384]        [268288, 333824)
// 524288            x_bf   bf16[8192*1024]      (16.8 MB)  [dead after gateup]
// 524288            y      bf16[16384*1024]     (33.5 MB)  [overlays x_bf/gw_bf]
// 17301504          gw_bf  bf16[8*2048*1024]    (33.6 MB)  [dead after gateup]
// 50855936          uw_bf  bf16[8*2048*1024]    (33.6 MB)  [dead after gateup]
// 84410368          dw_bf  bf16[8*1024*2048]    (33.6 MB)
// 117964800         act    bf16[16384*2048]     (67.1 MB)
// total need: 185,073,664 B. Every buffer rewritten before read each call.

__device__ __forceinline__ unsigned short f2bf(float f) {
    union { float f; unsigned u; } v; v.f = f;
    unsigned r = v.u + 0x7fffu + ((v.u >> 16) & 1u);   // RNE
    return (unsigned short)(r >> 16);
}

__device__ __forceinline__ void gl2lds16(const void* g, void* l) {
    __builtin_amdgcn_global_load_lds(
        (const __attribute__((address_space(1))) unsigned int*)g,
        (__attribute__((address_space(3))) unsigned int*)l, 16, 0, 0);
}

// ------------- router: logits, top-2, probs; emits x bf16. NO global atomics -------------
__global__ __launch_bounds__(256) void k_router(
    const float* __restrict__ x, const float* __restrict__ rw,
    int* __restrict__ topk_idx, float* __restrict__ topk_prob,
    unsigned short* __restrict__ x_bf)
{
    int wave = threadIdx.x >> 6;
    int lane = threadIdx.x & 63;
    int t = blockIdx.x * 4 + wave;

    const float4* xr = (const float4*)(x + (size_t)t * DD);
    float4 xv[4];
#pragma unroll
    for (int i = 0; i < 4; i++) xv[i] = xr[lane + 64 * i];

#pragma unroll
    for (int i = 0; i < 4; i++) {
        ushort4 u4 = make_ushort4(f2bf(xv[i].x), f2bf(xv[i].y),
                                  f2bf(xv[i].z), f2bf(xv[i].w));
        *(ushort4*)(x_bf + (size_t)t * DD + (lane + 64 * i) * 4) = u4;
    }

    float acc[NE];
#pragma unroll
    for (int e = 0; e < NE; e++) {
        const float4* wr = (const float4*)(rw + (size_t)e * DD);
        float s = 0.f;
#pragma unroll
        for (int i = 0; i < 4; i++) {
            float4 w = wr[lane + 64 * i];
            s += xv[i].x * w.x + xv[i].y * w.y + xv[i].z * w.z + xv[i].w * w.w;
        }
        acc[e] = s;
    }
#pragma unroll
    for (int e = 0; e < NE; e++) {
        float s = acc[e];
        for (int m = 32; m >= 1; m >>= 1) s += __shfl_xor(s, m);
        acc[e] = s;
    }
    if (lane == 0) {
        int b0 = 0; float l0 = acc[0];
#pragma unroll
        for (int e = 1; e < NE; e++) if (acc[e] > l0) { l0 = acc[e]; b0 = e; }
        int b1 = -1; float l1 = -3.0e38f;
#pragma unroll
        for (int e = 0; e < NE; e++) if (e != b0 && acc[e] > l1) { l1 = acc[e]; b1 = e; }
        float p0 = 1.f / (1.f + __expf(l1 - l0));
        float p1 = 1.f - p0;
        topk_idx[t * 2 + 0] = b0;  topk_idx[t * 2 + 1] = b1;
        topk_prob[t * 2 + 0] = p0; topk_prob[t * 2 + 1] = p1;
    }
}

// ------------- per-block histogram (LDS atomics only); SB blocks -------------
__global__ __launch_bounds__(256) void k_hist(
    const int* __restrict__ topk_idx, int* __restrict__ blk_hist)
{
    __shared__ int h[NE];
    if (threadIdx.x < NE) h[threadIdx.x] = 0;
    __syncthreads();
    int t = blockIdx.x * 256 + threadIdx.x;
    atomicAdd(&h[topk_idx[t * 2 + 0]], 1);
    atomicAdd(&h[topk_idx[t * 2 + 1]], 1);
    __syncthreads();
    if (threadIdx.x < NE)
        blk_hist[blockIdx.x * NE + threadIdx.x] = h[threadIdx.x];
}

// ------------- cross-block prefix + offsets (SB blocks of history) -------------
__global__ void k_scan2(const int* __restrict__ blk_hist, int* __restrict__ offsets,
                        int* __restrict__ base)
{
    __shared__ int totals[NE];
    int e = threadIdx.x;
    if (e < NE) {
        int run = 0;
        for (int b = 0; b < SB; b++) {
            base[b * NE + e] = run;
            run += blk_hist[b * NE + e];
        }
        totals[e] = run;
    }
    __syncthreads();
    if (threadIdx.x == 0) {
        int s = 0;
        for (int ee = 0; ee < NE; ee++) { offsets[ee] = s; s += totals[ee]; }
        offsets[NE] = s;
    }
    __syncthreads();
    if (e < NE) {
        int o = offsets[e];
        for (int b = 0; b < SB; b++) base[b * NE + e] += o;
    }
}

// ------------- scatter via LDS cursors (no contended global atomics); SB blocks -------------
__global__ __launch_bounds__(256) void k_scatter2(
    const int* __restrict__ topk_idx, const float* __restrict__ topk_prob,
    const int* __restrict__ base,
    int* __restrict__ token_list, float* __restrict__ prob_list,
    int* __restrict__ slot)
{
    __shared__ int cur[NE];
    if (threadIdx.x < NE) cur[threadIdx.x] = base[blockIdx.x * NE + threadIdx.x];
    __syncthreads();
    int t = blockIdx.x * 256 + threadIdx.x;
#pragma unroll
    for (int k = 0; k < 2; k++) {
        int e = topk_idx[t * 2 + k];
        int pos = atomicAdd(&cur[e], 1);   // LDS atomic
        token_list[pos] = t;
        prob_list[pos] = topk_prob[t * 2 + k];
        slot[t * 2 + k] = pos;
    }
}

// ---------------- merged f32 -> bf16 weight convert ----------------
__global__ __launch_bounds__(256) void k_cvt_all(
    const float* __restrict__ gw, const float* __restrict__ uw,
    const float* __restrict__ dw,
    unsigned short* __restrict__ gwb, unsigned short* __restrict__ uwb,
    unsigned short* __restrict__ dwb)
{
    constexpr int SEG = NE * HH * DD / 8;
    int i = blockIdx.x * blockDim.x + threadIdx.x;
    int stride = gridDim.x * blockDim.x;
    for (; i < 3 * SEG; i += stride) {
        const float* in; unsigned short* out; int j = i;
        if (j < SEG)            { in = gw; out = gwb; }
        else if (j < 2 * SEG)   { in = uw; out = uwb; j -= SEG; }
        else                    { in = dw; out = dwb; j -= 2 * SEG; }
        const float4* p = (const float4*)(in + (size_t)j * 8);
        float4 a = p[0], b = p[1];
        uint4 v;
        v.x = (unsigned)f2bf(a.x) | ((unsigned)f2bf(a.y) << 16);
        v.y = (unsigned)f2bf(a.z) | ((unsigned)f2bf(a.w) << 16);
        v.z = (unsigned)f2bf(b.x) | ((unsigned)f2bf(b.y) << 16);
        v.w = (unsigned)f2bf(b.z) | ((unsigned)f2bf(b.w) << 16);
        *(uint4*)(out + (size_t)j * 8) = v;
    }
}

// ================ gateup (r6 exact body): BM=128, B-rows=256, BK=64 ================
// Ring-3 LDS, depth-2 prefetch, counted vmcnt(6). Grid = 8 e x 64 m x 16 n (8192).
__global__ __launch_bounds__(512) void k_gateup_v3(
    const unsigned short* __restrict__ xb,
    const unsigned short* __restrict__ gwb,
    const unsigned short* __restrict__ uwb,
    const int* __restrict__ offsets,
    const int* __restrict__ token_list,
    unsigned short* __restrict__ act)
{
    extern __shared__ char lds[];   // 3 * 49152: per buf A 16K | B(G+U) 32K

    const int bid = blockIdx.x;
    const int e   = bid & 7;            // expert == XCD
    const int r   = bid >> 3;
    const int m   = r >> 4;             // 0..63 (worst-case n_e = 8192)
    const int n   = r & 15;
    const int off = offsets[e];
    const int n_e = offsets[e + 1] - off;
    const int m0  = m * 128;
    if (m0 >= n_e) return;
    const int n0g = n * 128;

    const int tid = threadIdx.x, lane = tid & 63, wid = tid >> 6;
    const int wm = wid >> 2, wn = wid & 3;          // 2m x 4n
    const int l8 = lane >> 3;
    const int colb = ((lane & 7) * 16) ^ (l8 << 4);

    const char* src[6];
    unsigned ldsoff[6];
#pragma unroll
    for (int i = 0; i < 6; i++) {
        int c = wid * 6 + i;
        if (c < 16) {
            int tr = c * 8 + l8;
            int rg = m0 + tr; if (rg > n_e - 1) rg = n_e - 1;
            int tok = token_list[off + rg];
            src[i] = (const char*)xb + (size_t)tok * (DD * 2) + colb;
            ldsoff[i] = c * 1024u;
        } else {
            int cb = c - 16;
            int tr = cb * 8 + l8;
            int wr = tr >> 6, w = tr & 63;
            const unsigned short* W = (w < 32) ? gwb : uwb;
            int wcol = n0g + wr * 32 + (w & 31);
            src[i] = (const char*)W + ((size_t)e * HH + wcol) * (DD * 2) + colb;
            ldsoff[i] = 16384u + cb * 1024u;
        }
    }

    f32x4 acc[4][4] = {};   // nj 0,1 = gate; 2,3 = up

#define GU_STAGE(T) do { char* b_ = lds + ((T) % 3) * 49152u; \
    _Pragma("unroll") for (int i_ = 0; i_ < 6; i_++) \
        gl2lds16(src[i_] + (T) * 128, b_ + ldsoff[i_]); } while (0)

    GU_STAGE(0);
    GU_STAGE(1);
    asm volatile("s_waitcnt vmcnt(6)" ::: "memory");
    __builtin_amdgcn_s_barrier();
    asm volatile("" ::: "memory");

    constexpr int NT = (DD * 2) / 128;   // 16 K-tiles
    for (int t = 0; t < NT; ++t) {
        if (t + 2 < NT) GU_STAGE(t + 2);
        const char* La = lds + (t % 3) * 49152u;
        const char* Lb = La + 16384;
        __builtin_amdgcn_s_setprio(1);
#pragma unroll
        for (int kk = 0; kk < 2; kk++) {
            const int kb = kk * 64 + (lane >> 4) * 16;
            bf16x8 af[4], bfr[4];
#pragma unroll
            for (int mi = 0; mi < 4; mi++) {
                int row = wm * 64 + mi * 16 + (lane & 15);
                af[mi] = *(const bf16x8*)(La + row * 128 + (kb ^ ((row & 7) << 4)));
            }
#pragma unroll
            for (int nj = 0; nj < 4; nj++) {
                int br = wn * 64 + nj * 16 + (lane & 15);
                bfr[nj] = *(const bf16x8*)(Lb + br * 128 + (kb ^ ((br & 7) << 4)));
            }
#pragma unroll
            for (int mi = 0; mi < 4; mi++)
#pragma unroll
                for (int nj = 0; nj < 4; nj++)
                    acc[mi][nj] = __builtin_amdgcn_mfma_f32_16x16x32_bf16(af[mi], bfr[nj], acc[mi][nj], 0, 0, 0);
        }
        __builtin_amdgcn_s_setprio(0);
        if (t + 2 < NT)      asm volatile("s_waitcnt vmcnt(6)" ::: "memory");
        else if (t + 1 < NT) asm volatile("s_waitcnt vmcnt(0)" ::: "memory");
        __builtin_amdgcn_s_barrier();
        asm volatile("" ::: "memory");
    }
#undef GU_STAGE

    // epilogue: silu(g)*u -> act bf16
#pragma unroll
    for (int mi = 0; mi < 4; mi++) {
#pragma unroll
        for (int r2 = 0; r2 < 4; r2++) {
            int row = wm * 64 + mi * 16 + (lane >> 4) * 4 + r2;
            int rg = m0 + row;
            if (rg >= n_e) continue;
            size_t rowbase = (size_t)(off + rg) * HH + n0g + wn * 32;
#pragma unroll
            for (int nj = 0; nj < 2; nj++) {
                float gg = acc[mi][nj][r2];
                float uu = acc[mi][nj + 2][r2];
                float sv = gg / (1.f + __expf(-gg)) * uu;
                act[rowbase + nj * 16 + (lane & 15)] = f2bf(sv);
            }
        }
    }
}

// ================ down (r8 m97-style): 128x128, BK=64, 32 KB LDS, 4 blocks/CU TLP ================
// 4 waves (2m x 2n), wave 64x64. Single-buffered 2-barrier K-loop; multi-block
// occupancy provides the latency hiding (contiguous A — the regime where this wins).
// Grid = 8 e x 8 n x 64 m (4096, e = bid&7 pinned to XCD, m-inner).
__global__ __launch_bounds__(256) void k_down_v5(
    const unsigned short* __restrict__ act,
    const unsigned short* __restrict__ dwb,
    const int* __restrict__ offsets,
    unsigned short* __restrict__ y)
{
    __shared__ char lds[32768];   // A [0,16K) | B [16K,32K)

    const int bid = blockIdx.x;
    const int e   = bid & 7;
    const int rem = bid >> 3;
    const int n   = rem >> 6;            // 8 n-slices of 128 D-cols
    const int m   = rem & 63;            // m-inner: consecutive blocks share B panel
    const int off = offsets[e];
    const int n_e = offsets[e + 1] - off;
    const int m0  = m * 128;
    if (m0 >= n_e) return;
    const int n0  = n * 128;

    const int tid = threadIdx.x, lane = tid & 63, wid = tid >> 6;
    const int wm = wid >> 1, wn = wid & 1;
    const int l8 = lane >> 3, l15 = lane & 15;
    const int colb = ((lane & 7) * 16) ^ (l8 << 4);

    const char* src[8];
#pragma unroll
    for (int i = 0; i < 8; i++) {
        int c = wid * 8 + i;
        if (c < 16) {
            int rg = m0 + c * 8 + l8; if (rg > n_e - 1) rg = n_e - 1;
            src[i] = (const char*)act + (size_t)(off + rg) * (HH * 2) + colb;
        } else {
            int tr = (c - 16) * 8 + l8;
            src[i] = (const char*)dwb + ((size_t)e * DD + n0 + tr) * (HH * 2) + colb;
        }
    }

    f32x4 acc[4][4] = {};

    constexpr int NT = (HH * 2) / 128;   // 32 K-tiles
    for (int t = 0; t < NT; ++t) {
        __syncthreads();   // prior tile's ds_reads done before overwrite
#pragma unroll
        for (int i = 0; i < 8; i++)
            gl2lds16(src[i] + t * 128, lds + (wid * 8 + i) * 1024);
        __syncthreads();   // compiler drains vmcnt before barrier
#pragma unroll
        for (int kk = 0; kk < 2; kk++) {
            const int kb = kk * 64 + (lane >> 4) * 16;
            bf16x8 af[4], bfr[4];
#pragma unroll
            for (int mi = 0; mi < 4; mi++) {
                int row = wm * 64 + mi * 16 + l15;
                af[mi] = *(const bf16x8*)(lds + row * 128 + (kb ^ ((row & 7) << 4)));
            }
#pragma unroll
            for (int nj = 0; nj < 4; nj++) {
                int br = wn * 64 + nj * 16 + l15;
                bfr[nj] = *(const bf16x8*)(lds + 16384 + br * 128 + (kb ^ ((br & 7) << 4)));
            }
#pragma unroll
            for (int mi = 0; mi < 4; mi++)
#pragma unroll
                for (int nj = 0; nj < 4; nj++)
                    acc[mi][nj] = __builtin_amdgcn_mfma_f32_16x16x32_bf16(
                        af[mi], bfr[nj], acc[mi][nj], 0, 0, 0);
        }
    }

    // epilogue: y[grouped row] = result (bf16; combine applies probs)
#pragma unroll
    for (int mi = 0; mi < 4; mi++) {
#pragma unroll
        for (int r2 = 0; r2 < 4; r2++) {
            int row = wm * 64 + mi * 16 + (lane >> 4) * 4 + r2;
            int rg = m0 + row;
            if (rg >= n_e) continue;
            size_t ybase = (size_t)(off + rg) * DD + n0 + wn * 64;
#pragma unroll
            for (int nj = 0; nj < 4; nj++)
                y[ybase + nj * 16 + l15] = f2bf(acc[mi][nj][r2]);
        }
    }
}

// ---------------- combine: out[t] = p0*y[slot0] + p1*y[slot1] ----------------
__global__ __launch_bounds__(256) void k_combine(
    const unsigned short* __restrict__ y,
    const int* __restrict__ slot,
    const float* __restrict__ topk_prob,
    float* __restrict__ out)
{
    int t = blockIdx.x * 2 + (threadIdx.x >> 7);
    int i = threadIdx.x & 127;
    int s0 = slot[t * 2 + 0], s1 = slot[t * 2 + 1];
    float p0 = topk_prob[t * 2 + 0], p1 = topk_prob[t * 2 + 1];
    bf16x8 a = *(const bf16x8*)(y + (size_t)s0 * DD + i * 8);
    bf16x8 b = *(const bf16x8*)(y + (size_t)s1 * DD + i * 8);
    float o[8];
#pragma unroll
    for (int j = 0; j < 8; j++) {
        union { unsigned u; float f; } va, vb;
        va.u = ((unsigned)(unsigned short)a[j]) << 16;
        vb.u = ((unsigned)(unsigned short)b[j]) << 16;
        o[j] = p0 * va.f + p1 * vb.f;
    }
    float4* op = (float4*)(out + (size_t)t * DD + i * 8);
    op[0] = make_float4(o[0], o[1], o[2], o[3]);
    op[1] = make_float4(o[4], o[5], o[6], o[7]);
}

extern "C" void kernel_launch(void* const* d_in, const int* in_sizes, int n_in,
                              void* d_out, int out_size, void* d_ws, size_t ws_size,
                              hipStream_t stream) {
    const float* x  = (const float*)d_in[0];
    const float* rw = (const float*)d_in[1];
    const float* gw = (const float*)d_in[2];
    const float* uw = (const float*)d_in[3];
    const float* dw = (const float*)d_in[4];
    float* out = (float*)d_out;

    char* ws = (char*)d_ws;
    int*   topk_idx   = (int*)(ws + 0);
    float* topk_prob  = (float*)(ws + 65536);
    int*   offsets    = (int*)(ws + 131072);
    int*   blk_hist   = (int*)(ws + 131136);
    int*   base       = (int*)(ws + 133184);
    int*   token_list = (int*)(ws + 137216);
    float* prob_list  = (float*)(ws + 202752);
    int*   slot       = (int*)(ws + 268288);

    unsigned short* x_bf  = (unsigned short*)(ws + 524288);
    unsigned short* y     = (unsigned short*)(ws + 524288);  // overlays x_bf/gw_bf (dead)
    unsigned short* gw_bf = (unsigned short*)(ws + 17301504);
    unsigned short* uw_bf = (unsigned short*)(ws + 50855936);
    unsigned short* dw_bf = (unsigned short*)(ws + 84410368);
    unsigned short* act   = (unsigned short*)(ws + 117964800);

    k_router<<<TOK / 4, 256, 0, stream>>>(x, rw, topk_idx, topk_prob, x_bf);
    k_hist<<<SB, 256, 0, stream>>>(topk_idx, blk_hist);
    k_scan2<<<1, 64, 0, stream>>>(blk_hist, offsets, base);
    k_scatter2<<<SB, 256, 0, stream>>>(topk_idx, topk_prob, base,
                                       token_list, prob_list, slot);

    k_cvt_all<<<2048, 256, 0, stream>>>(gw, uw, dw, gw_bf, uw_bf, dw_bf);

    // gateup: 8192 blocks = 8 e x 64 m x 16 n (n-inner), r6 body
    k_gateup_v3<<<8192, 512, 147456, stream>>>(x_bf, gw_bf, uw_bf, offsets,
                                               token_list, act);
    // down: 4096 blocks = 8 e x 8 n x 64 m (m-inner), m97-TLP structure
    k_down_v5<<<4096, 256, 0, stream>>>(act, dw_bf, offsets, y);

    k_combine<<<TOK / 2, 256, 0, stream>>>(y, slot, topk_prob, out);
}